// Round 5
// baseline (173.701 us; speedup 1.0000x reference)
//
#include <hip/hip_runtime.h>
#include <hip/hip_bf16.h>
#include <stdint.h>

#define N_SAMPLES 4096
#define M_ROWS 16
#define K_DIM 256
#define H_DIM 256
#define N_CATS 64
#define SPB 4                                        // samples per group (64 rows)
#define MAX_PADDED (N_SAMPLES + N_CATS * (SPB - 1))  // 4288
#define AROW 264                                     // 256+8 halfs per LDS row
#define REPS 8                                       // blocks per category
#define GEMM_BLOCKS (N_CATS * REPS)                  // 512 (2 per CU)

typedef _Float16 half8 __attribute__((ext_vector_type(8)));
typedef _Float16 half4 __attribute__((ext_vector_type(4)));
typedef float floatx4 __attribute__((ext_vector_type(4)));

// ---- workspace layout ----
#define WT_BYTES ((size_t)N_CATS * K_DIM * H_DIM * 2)  // 8 MB f16 W^T
#define ORD_OFF  WT_BYTES                              // MAX_PADDED ints (16B-aligned)
#define POFF_OFF (ORD_OFF + (size_t)MAX_PADDED * 4)    // 65 ints
#define WS_NEED  (POFF_OFF + 65 * 4)

// ---------------- fused prep: transpose (blocks 0..1023) + bucketing (block 1024) ----
__global__ __launch_bounds__(256)
void prep_combined(const float* __restrict__ W, _Float16* __restrict__ Wt,
                   const int* __restrict__ cat, int* __restrict__ ord,
                   int* __restrict__ gpoffs) {
  const int tid = threadIdx.x;
  if (blockIdx.x < 1024) {
    __shared__ _Float16 t[64][72];
    const int bid = blockIdx.x;
    const int c  = bid >> 4;
    const int kb = (bid >> 2) & 3;
    const int hb = bid & 3;
    const int r  = tid >> 2;
    const int cg = (tid & 3) * 16;
    const float* src = W + ((size_t)c << 16) + (size_t)(kb * 64 + r) * 256 + hb * 64 + cg;
#pragma unroll
    for (int j = 0; j < 16; j += 4) {
      float4 v = *(const float4*)(src + j);
      t[r][cg + j + 0] = (_Float16)v.x;
      t[r][cg + j + 1] = (_Float16)v.y;
      t[r][cg + j + 2] = (_Float16)v.z;
      t[r][cg + j + 3] = (_Float16)v.w;
    }
    __syncthreads();
    _Float16* dst = Wt + ((size_t)c << 16) + (size_t)(hb * 64 + r) * 256 + kb * 64 + cg;
    half8 o0, o1;
#pragma unroll
    for (int j = 0; j < 8; j++) o0[j] = t[cg + j][r];
#pragma unroll
    for (int j = 0; j < 8; j++) o1[j] = t[cg + 8 + j][r];
    *(half8*)(dst) = o0;
    *(half8*)(dst + 8) = o1;
  } else {
    __shared__ int hist[N_CATS];
    __shared__ int poffs[N_CATS + 1];
    __shared__ int curs[N_CATS];
    if (tid < N_CATS) hist[tid] = 0;
    for (int i = tid; i < MAX_PADDED; i += 256) ord[i] = -1;
    __syncthreads();
    for (int i = tid; i < N_SAMPLES; i += 256) atomicAdd(&hist[cat[i]], 1);
    __syncthreads();
    if (tid == 0) {
      int run = 0;
      for (int c = 0; c < N_CATS; c++) {
        poffs[c] = run;
        run += ((hist[c] + SPB - 1) / SPB) * SPB;
      }
      poffs[N_CATS] = run;
    }
    if (tid < N_CATS) curs[tid] = 0;
    __syncthreads();
    if (tid <= N_CATS) gpoffs[tid] = poffs[tid];
    for (int i = tid; i < N_SAMPLES; i += 256) {
      int c = cat[i];
      int p = poffs[c] + atomicAdd(&curs[c], 1);
      ord[p] = i;
    }
  }
}

// ---------------- persistent category-pinned GEMM ----------------
// block = 512 threads (8 waves), pinned to one category, full 256 cols.
// B fragments (bf[8][2], wave wid owns cols wid*32..+31) are LOOP-INVARIANT ->
// held in VGPRs across the whole group loop (allocator cannot sink them).
// A double-buffered in LDS: compute group g from sA[p] while next group's x
// loads (global->VGPR fp32) and fp32->f16 ds_writes fill sA[p^1].
// ONE barrier per group; MFMA phase never waits on a just-issued global load.
// Replicas of a category share an XCD (blockIdx&7) for Wt L2 locality.
__global__ __launch_bounds__(512, 2)
void gemm_persist(const float* __restrict__ x, const float* __restrict__ bias,
                  const _Float16* __restrict__ Wt, const int* __restrict__ ord,
                  const int* __restrict__ gpoffs, float* __restrict__ out) {
  __shared__ __align__(16) _Float16 sA[2][64 * AROW];  // 66 KB

  const int tid = threadIdx.x;
  const int b = blockIdx.x;
  const int xcd = b & 7;
  const int kk = b >> 3;               // 0..63
  const int cat = xcd * 8 + (kk >> 3); // 8 cats per XCD
  const int rep = kk & 7;

  const int gbeg = gpoffs[cat] >> 2;
  const int gend = gpoffs[cat + 1] >> 2;
  int g = gbeg + rep;
  if (g >= gend) return;               // block-uniform

  const int wid  = tid >> 6;
  const int lane = tid & 63;
  const int l15  = lane & 15;
  const int quad = lane >> 4;

  const _Float16* wbase = Wt + ((size_t)cat << 16);

  // ---- loop-invariant B fragments + bias ----
  half8 bf[8][2];
#pragma unroll
  for (int kt = 0; kt < 8; kt++)
#pragma unroll
    for (int nt = 0; nt < 2; nt++) {
      const int col = wid * 32 + nt * 16 + l15;
      bf[kt][nt] = *(const half8*)(wbase + (size_t)col * K_DIM + kt * 32 + quad * 8);
    }
  float bv[2];
#pragma unroll
  for (int nt = 0; nt < 2; nt++)
    bv[nt] = bias[cat * H_DIM + wid * 32 + nt * 16 + l15];

  // ---- prologue: stage group g into sA[0] ----
  int4 sm = *(const int4*)(ord + g * 4);
#pragma unroll
  for (int j = 0; j < 8; j++) {
    const int f = j * 512 + tid;
    const int row = f >> 6;            // 0..63 (uniform per wave-instr)
    const int col4 = f & 63;           // float4 index within row
    const int s = (j >> 1) == 0 ? sm.x : (j >> 1) == 1 ? sm.y : (j >> 1) == 2 ? sm.z : sm.w;
    float4 v = (s >= 0)
        ? *(const float4*)(x + ((size_t)s << 12) + (size_t)(row & 15) * 256 + col4 * 4)
        : make_float4(0.f, 0.f, 0.f, 0.f);
    half4 h;
    h[0] = (_Float16)v.x; h[1] = (_Float16)v.y;
    h[2] = (_Float16)v.z; h[3] = (_Float16)v.w;
    *(half4*)&sA[0][row * AROW + col4 * 4] = h;
  }
  __syncthreads();

  int p = 0;
  while (true) {
    const int gn = g + REPS;
    const bool has_next = (gn < gend);  // block-uniform

    // ---- prefetch next group's A into VGPRs (overlaps MFMA below) ----
    int4 smn = sm;
    float4 av[8];
    if (has_next) {
      smn = *(const int4*)(ord + gn * 4);
#pragma unroll
      for (int j = 0; j < 8; j++) {
        const int f = j * 512 + tid;
        const int row = f >> 6;
        const int col4 = f & 63;
        const int s = (j >> 1) == 0 ? smn.x : (j >> 1) == 1 ? smn.y : (j >> 1) == 2 ? smn.z : smn.w;
        av[j] = (s >= 0)
            ? *(const float4*)(x + ((size_t)s << 12) + (size_t)(row & 15) * 256 + col4 * 4)
            : make_float4(0.f, 0.f, 0.f, 0.f);
      }
    }

    // ---- compute current group from sA[p] ----
    floatx4 acc[4][2];
#pragma unroll
    for (int i = 0; i < 4; i++)
#pragma unroll
      for (int j = 0; j < 2; j++)
#pragma unroll
        for (int e = 0; e < 4; e++) acc[i][j][e] = 0.0f;
#pragma unroll
    for (int kt = 0; kt < 8; kt++) {
      half8 af[4];
#pragma unroll
      for (int mt = 0; mt < 4; mt++)
        af[mt] = *(const half8*)&sA[p][(mt * 16 + l15) * AROW + kt * 32 + quad * 8];
#pragma unroll
      for (int mt = 0; mt < 4; mt++)
#pragma unroll
        for (int nt = 0; nt < 2; nt++)
          acc[mt][nt] = __builtin_amdgcn_mfma_f32_16x16x32_f16(af[mt], bf[kt][nt], acc[mt][nt], 0, 0, 0);
    }

    // ---- convert + write next A into sA[p^1] (no barrier needed before) ----
    if (has_next) {
#pragma unroll
      for (int j = 0; j < 8; j++) {
        const int f = j * 512 + tid;
        const int row = f >> 6;
        const int col4 = f & 63;
        half4 h;
        h[0] = (_Float16)av[j].x; h[1] = (_Float16)av[j].y;
        h[2] = (_Float16)av[j].z; h[3] = (_Float16)av[j].w;
        *(half4*)&sA[p ^ 1][row * AROW + col4 * 4] = h;
      }
    }

    // ---- epilogue: C/D layout col=lane&15, row=quad*4+reg ----
    const int srow[4] = {sm.x, sm.y, sm.z, sm.w};
#pragma unroll
    for (int mt = 0; mt < 4; mt++) {
      const int s = srow[mt];
      if (s < 0) continue;  // pad rows (block-uniform)
      float* obase = out + ((size_t)s << 12);
#pragma unroll
      for (int nt = 0; nt < 2; nt++) {
        const int col = wid * 32 + nt * 16 + l15;
#pragma unroll
        for (int rr = 0; rr < 4; rr++) {
          const int row = quad * 4 + rr;
          obase[(size_t)row * H_DIM + col] = acc[mt][nt][rr] + bv[nt];
        }
      }
    }

    if (!has_next) break;
    sm = smn;
    g = gn;
    p ^= 1;
    __syncthreads();  // the one barrier per group
  }
}

// ---------------- fallback (ws too small): naive fp32 ----------------
__global__ __launch_bounds__(256)
void naive_kernel(const float* __restrict__ x, const int* __restrict__ cat,
                  const float* __restrict__ W, const float* __restrict__ bias,
                  float* __restrict__ out) {
  __shared__ float sx[16 * 256];
  const int n = blockIdx.x;
  const int tid = threadIdx.x;
  const int c = cat[n];
  const float* xs = x + (size_t)n * 16 * 256;
  for (int i = tid; i < 16 * 256; i += 256) sx[i] = xs[i];
  __syncthreads();
  const float* Wc = W + ((size_t)c << 16);
  float accv[16];
  float bv = bias[c * 256 + tid];
#pragma unroll
  for (int m = 0; m < 16; m++) accv[m] = bv;
  for (int k = 0; k < 256; k++) {
    float w = Wc[(size_t)k * 256 + tid];
#pragma unroll
    for (int m = 0; m < 16; m++) accv[m] += sx[m * 256 + k] * w;
  }
#pragma unroll
  for (int m = 0; m < 16; m++) out[((size_t)n * 16 + m) * 256 + tid] = accv[m];
}

// ---------------- launcher ----------------
extern "C" void kernel_launch(void* const* d_in, const int* in_sizes, int n_in,
                              void* d_out, int out_size, void* d_ws, size_t ws_size,
                              hipStream_t stream) {
  const float* x    = (const float*)d_in[0];
  const int*   cat  = (const int*)d_in[1];
  const float* W    = (const float*)d_in[2];
  const float* bias = (const float*)d_in[3];
  float* out = (float*)d_out;

  if (ws_size < WS_NEED) {
    naive_kernel<<<N_SAMPLES, 256, 0, stream>>>(x, cat, W, bias, out);
    return;
  }

  char* ws = (char*)d_ws;
  _Float16* Wt = (_Float16*)ws;
  int* ord    = (int*)(ws + ORD_OFF);
  int* gpoffs = (int*)(ws + POFF_OFF);

  prep_combined<<<1025, 256, 0, stream>>>(W, Wt, cat, ord, gpoffs);
  gemm_persist<<<GEMM_BLOCKS, 512, 0, stream>>>(x, bias, Wt, ord, gpoffs, out);
}